// Round 1
// baseline (2681.964 us; speedup 1.0000x reference)
//
#include <hip/hip_runtime.h>

#define B_   64
#define D_   256
#define HW_  1024
#define N_   65536
#define K_   1024
#define ND_  16777216
#define MARGIN 2e-4f

// ---------------- k_init: e2[k] = ||e_k||^2, zero counts/loss ----------------
__global__ __launch_bounds__(256) void k_init(const float* __restrict__ E,
                                              float* __restrict__ e2f,
                                              int* __restrict__ counts,
                                              double* __restrict__ loss_acc) {
    int k = blockIdx.x * 256 + threadIdx.x;   // grid = 4*256 = 1024
    if (k < K_) {
        const float4* er = (const float4*)(E + (size_t)k * D_);
        double s = 0.0;
        for (int j = 0; j < D_ / 4; ++j) {
            float4 v = er[j];
            s += (double)v.x * v.x + (double)v.y * v.y
               + (double)v.z * v.z + (double)v.w * v.w;
        }
        e2f[k]    = (float)s;
        counts[k] = 0;
        if (k == 0) *loss_acc = 0.0;
    }
}

// ---------------- k_phase1: approx scores + top-2 + flag ----------------
// block = 64 rows (one b, 64 consecutive hw); 4 waves split K into 4x256.
__global__ __launch_bounds__(256) void k_phase1(const float* __restrict__ Z,
                                                const float* __restrict__ E,
                                                const float* __restrict__ e2f,
                                                int* __restrict__ idx,
                                                unsigned char* __restrict__ flag) {
    __shared__ float zt[D_][64];          // 64 KB, transposed: zt[d][row]
    int t = threadIdx.x;
    int rowbase = blockIdx.x * 64;
    int b   = rowbase >> 10;
    int hw0 = rowbase & (HW_ - 1);
    const float* zb = Z + (size_t)b * D_ * HW_ + hw0;

    int l = t & 63, dq = t >> 6;
    // stage z tile: wave-uniform d, lane = row -> coalesced 256B loads
    for (int j = 0; j < 64; ++j) {
        int d = dq + 4 * j;
        zt[d][l] = zb[(size_t)d * HW_ + l];
    }
    __syncthreads();

    int kbase = __builtin_amdgcn_readfirstlane((t >> 6) << 8);  // wave*256

    float m1 = 3.4e38f, m2 = 3.4e38f;
    int   i1 = 0;

    for (int kt = 0; kt < 16; ++kt) {     // 16 tiles of 16 k
        int k0 = kbase + kt * 16;
        float acc[16];
        #pragma unroll
        for (int i = 0; i < 16; ++i) acc[i] = 0.f;

        for (int dc = 0; dc < 16; ++dc) { // 16 chunks of 16 d
            float zreg[16];
            #pragma unroll
            for (int i = 0; i < 16; ++i) zreg[i] = zt[dc * 16 + i][l];
            #pragma unroll
            for (int kk = 0; kk < 16; ++kk) {
                const float* er = E + (size_t)(k0 + kk) * D_ + dc * 16; // uniform -> s_load
                #pragma unroll
                for (int i = 0; i < 16; ++i)
                    acc[kk] = fmaf(er[i], zreg[i], acc[kk]);
            }
        }
        #pragma unroll
        for (int kk = 0; kk < 16; ++kk) {
            float s = fmaf(-2.f, acc[kk], e2f[k0 + kk]);
            if (s < m1)      { m2 = m1; m1 = s; i1 = k0 + kk; }
            else if (s < m2) { m2 = s; }
        }
    }

    // cross-wave top-2 merge (reuse zt as scratch)
    __syncthreads();
    float* red  = &zt[0][0];
    int*   ired = (int*)red;
    int wave = t >> 6;
    red[wave * 64 + l]        = m1;
    red[256 + wave * 64 + l]  = m2;
    ired[512 + wave * 64 + l] = i1;
    __syncthreads();

    if (t < 64) {
        float M1 = red[t], M2 = red[256 + t];
        int   I1 = ired[512 + t];
        #pragma unroll
        for (int w = 1; w < 4; ++w) {
            float a1 = red[w * 64 + t], a2 = red[256 + w * 64 + t];
            int   ai = ired[512 + w * 64 + t];
            if (a1 < M1) { M2 = fminf(M1, a2); M1 = a1; I1 = ai; }
            else         { M2 = fminf(M2, a1); }
        }
        int n = rowbase + t;
        idx[n]  = I1;
        flag[n] = (M2 - M1 < MARGIN) ? 1 : 0;
    }
}

// ---------------- k_rescan: exact f64 full-K re-rank of flagged rows ----------------
__global__ __launch_bounds__(256) void k_rescan(const float* __restrict__ Z,
                                                const float* __restrict__ E,
                                                const unsigned char* __restrict__ flag,
                                                int* __restrict__ idx) {
    __shared__ float  zrow[D_];
    __shared__ double wmin[4];
    __shared__ int    widx[4];
    int t = threadIdx.x, wave = t >> 6, l = t & 63;

    for (int n = blockIdx.x; n < N_; n += gridDim.x) {
        if (!flag[n]) continue;            // uniform across block
        int b = n >> 10, hw = n & (HW_ - 1);
        const float* zp = Z + (size_t)b * D_ * HW_ + hw;
        zrow[t] = zp[(size_t)t * HW_];
        __syncthreads();

        double bm = 1e300; int bi = 0;
        for (int kk = 0; kk < 256; ++kk) { // wave handles k in [wave*256, +256), ascending
            int k = (wave << 8) + kk;
            const float* er = E + (size_t)k * D_;
            double s = 0.0;
            #pragma unroll
            for (int q = 0; q < 4; ++q) {
                int d = l + q * 64;
                double dz = (double)zrow[d] - (double)er[d];
                s = fma(dz, dz, s);
            }
            #pragma unroll
            for (int off = 32; off; off >>= 1) s += __shfl_xor(s, off, 64);
            if (s < bm) { bm = s; bi = k; } // strict < : first (lowest k) wins ties
        }
        if (l == 0) { wmin[wave] = bm; widx[wave] = bi; }
        __syncthreads();
        if (t == 0) {
            double M = wmin[0]; int I = widx[0];
            #pragma unroll
            for (int w = 1; w < 4; ++w)
                if (wmin[w] < M) { M = wmin[w]; I = widx[w]; }
            idx[n] = I;
        }
        __syncthreads();
    }
}

// ---------------- k_gather: z_q output (NCHW), loss partials, counts ----------------
__global__ __launch_bounds__(256) void k_gather(const float* __restrict__ Z,
                                                const float* __restrict__ E,
                                                const int* __restrict__ idx,
                                                float* __restrict__ out_zq,
                                                int* __restrict__ counts,
                                                double* __restrict__ loss_acc) {
    __shared__ int    sidx[64];
    __shared__ double wls[4];
    int t = threadIdx.x;
    int rowbase = blockIdx.x * 64;
    int b = rowbase >> 10, hw0 = rowbase & (HW_ - 1);
    int l = t & 63, cq = t >> 6;

    if (t < 64) sidx[t] = idx[rowbase + t];
    __syncthreads();
    int i_l = sidx[l];

    const float* zb = Z      + (size_t)b * D_ * HW_ + hw0;
    float*       ob = out_zq + (size_t)b * D_ * HW_ + hw0;

    double ls = 0.0;
    for (int j = 0; j < 64; ++j) {
        int c = cq * 64 + j;
        float e = E[(size_t)i_l * D_ + c];          // gather (L2-hot, 1 MB table)
        float z = zb[(size_t)c * HW_ + l];          // coalesced
        ob[(size_t)c * HW_ + l] = e;                // coalesced
        double dz = (double)z - (double)e;
        ls = fma(dz, dz, ls);
    }
    #pragma unroll
    for (int off = 32; off; off >>= 1) ls += __shfl_xor(ls, off, 64);
    if (l == 0) wls[cq] = ls;
    __syncthreads();
    if (t == 0) atomicAdd(loss_acc, wls[0] + wls[1] + wls[2] + wls[3]);
    if (t < 64) atomicAdd(&counts[sidx[t]], 1);
}

// ---------------- k_final: loss & perplexity scalars ----------------
__global__ __launch_bounds__(256) void k_final(const int* __restrict__ counts,
                                               const double* __restrict__ loss_acc,
                                               float* __restrict__ out) {
    __shared__ double sh[256];
    int t = threadIdx.x;
    double s = 0.0;
    for (int k = t; k < K_; k += 256) {
        double p = (double)counts[k] / (double)N_;
        s += p * log(p + 1e-10);
    }
    sh[t] = s; __syncthreads();
    for (int off = 128; off; off >>= 1) {
        if (t < off) sh[t] += sh[t + off];
        __syncthreads();
    }
    if (t == 0) {
        out[0]       = (float)((*loss_acc) / (double)ND_ * 1.25);
        out[1 + ND_] = (float)exp(-sh[0]);
    }
}

extern "C" void kernel_launch(void* const* d_in, const int* in_sizes, int n_in,
                              void* d_out, int out_size, void* d_ws, size_t ws_size,
                              hipStream_t stream) {
    (void)in_sizes; (void)n_in; (void)out_size; (void)ws_size;
    const float* Z = (const float*)d_in[0];
    const float* E = (const float*)d_in[1];
    float* out = (float*)d_out;

    char* ws = (char*)d_ws;
    float*         e2f      = (float*)ws;                     // 4 KB
    int*           idx      = (int*)(ws + 4096);              // 256 KB
    unsigned char* flag     = (unsigned char*)(ws + 266240);  // 64 KB
    int*           counts   = (int*)(ws + 331776);            // 4 KB
    double*        loss_acc = (double*)(ws + 335872);         // 8 B

    k_init  <<<dim3(4),    dim3(256), 0, stream>>>(E, e2f, counts, loss_acc);
    k_phase1<<<dim3(1024), dim3(256), 0, stream>>>(Z, E, e2f, idx, flag);
    k_rescan<<<dim3(1024), dim3(256), 0, stream>>>(Z, E, flag, idx);
    k_gather<<<dim3(1024), dim3(256), 0, stream>>>(Z, E, idx, out + 1, counts, loss_acc);
    k_final <<<1,          dim3(256), 0, stream>>>(counts, loss_acc, out);
}

// Round 2
// 2488.068 us; speedup vs baseline: 1.0779x; 1.0779x over previous
//
#include <hip/hip_runtime.h>

#define B_   64
#define D_   256
#define HW_  1024
#define N_   65536
#define K_   1024
#define ND_  16777216
#define MARGIN 2e-4f

typedef __attribute__((ext_vector_type(8))) short bf16x8;
typedef __attribute__((ext_vector_type(4))) float f32x4;

__device__ inline unsigned short bf16_rne(float v) {
    unsigned u = __float_as_uint(v);
    return (unsigned short)((u + 0x7FFF + ((u >> 16) & 1)) >> 16);
}
__device__ inline float bf16_to_f(unsigned short h) {
    return __uint_as_float(((unsigned)h) << 16);
}

// ---------------- k_init: split E -> bf16 hi/lo tables, e2[k], zero counts/loss ----
__global__ __launch_bounds__(256) void k_init(const float* __restrict__ E,
                                              unsigned short* __restrict__ Ehi,
                                              unsigned short* __restrict__ Elo,
                                              float* __restrict__ e2f,
                                              int* __restrict__ counts,
                                              double* __restrict__ loss_acc) {
    __shared__ double sh[256];
    int k = blockIdx.x, t = threadIdx.x;      // grid = 1024
    float v = E[(size_t)k * D_ + t];
    unsigned short h = bf16_rne(v);
    float res = v - bf16_to_f(h);
    Ehi[(size_t)k * D_ + t] = h;
    Elo[(size_t)k * D_ + t] = bf16_rne(res);
    sh[t] = (double)v * v;
    __syncthreads();
    for (int off = 128; off; off >>= 1) {
        if (t < off) sh[t] += sh[t + off];
        __syncthreads();
    }
    if (t == 0) {
        e2f[k] = (float)sh[0];
        counts[k] = 0;
        if (k == 0) *loss_acc = 0.0;
    }
}

// ---------------- k_phase1: split-bf16 MFMA scores + top-2 + flag ----------------
// 4 waves/block, wave owns 16 rows x all 1024 codes. A in registers (hi+lo).
__global__ __launch_bounds__(256) void k_phase1(const float* __restrict__ Z,
                                                const unsigned short* __restrict__ Ehi,
                                                const unsigned short* __restrict__ Elo,
                                                const float* __restrict__ e2f,
                                                int* __restrict__ idx,
                                                unsigned char* __restrict__ flag) {
    int t = threadIdx.x;
    int w = t >> 6, l = t & 63;
    int kq = l >> 4;                       // 0..3 : k-offset group
    int rowbase = blockIdx.x * 64;
    int row = rowbase + w * 16 + (l & 15); // this lane's A row
    int b = row >> 10, hw = row & (HW_ - 1);
    const float* zp = Z + (size_t)b * D_ * HW_ + hw;

    // ---- load A fragments (hi/lo split), full D in registers ----
    bf16x8 a_hi[8], a_lo[8];
    for (int ks = 0; ks < 8; ++ks) {
        #pragma unroll
        for (int j = 0; j < 8; ++j) {
            int d = ks * 32 + kq * 8 + j;
            float v = zp[(size_t)d * HW_];
            unsigned short h = bf16_rne(v);
            a_hi[ks][j] = (short)h;
            a_lo[ks][j] = (short)bf16_rne(v - bf16_to_f(h));
        }
    }

    float m1[4], m2[4]; int i1[4];
    #pragma unroll
    for (int r = 0; r < 4; ++r) { m1[r] = 3.4e38f; m2[r] = 3.4e38f; i1[r] = 0; }

    const unsigned short* bh_base = Ehi + (size_t)(l & 15) * D_ + kq * 8;
    const unsigned short* bl_base = Elo + (size_t)(l & 15) * D_ + kq * 8;

    for (int nt = 0; nt < 64; ++nt) {
        int c0 = nt * 16;
        const unsigned short* bh = bh_base + (size_t)c0 * D_;
        const unsigned short* bl = bl_base + (size_t)c0 * D_;
        f32x4 acc = {0.f, 0.f, 0.f, 0.f};
        #pragma unroll
        for (int ks = 0; ks < 8; ++ks) {
            bf16x8 vh = *(const bf16x8*)(bh + ks * 32);
            bf16x8 vl = *(const bf16x8*)(bl + ks * 32);
            acc = __builtin_amdgcn_mfma_f32_16x16x32_bf16(a_hi[ks], vh, acc, 0, 0, 0);
            acc = __builtin_amdgcn_mfma_f32_16x16x32_bf16(a_lo[ks], vh, acc, 0, 0, 0);
            acc = __builtin_amdgcn_mfma_f32_16x16x32_bf16(a_hi[ks], vl, acc, 0, 0, 0);
        }
        float e2 = e2f[c0 + (l & 15)];
        int c = c0 + (l & 15);
        #pragma unroll
        for (int r = 0; r < 4; ++r) {
            float s = fmaf(-2.f, acc[r], e2);
            if (s < m1[r])      { m2[r] = m1[r]; m1[r] = s; i1[r] = c; }
            else if (s < m2[r]) { m2[r] = s; }
        }
        __syncthreads();   // keep 4 waves' n-tile windows aligned -> L1 reuse of E
    }

    // ---- merge top-2 across the 16 lanes sharing each row ----
    #pragma unroll
    for (int off = 1; off < 16; off <<= 1) {
        #pragma unroll
        for (int r = 0; r < 4; ++r) {
            float om1 = __shfl_xor(m1[r], off, 64);
            float om2 = __shfl_xor(m2[r], off, 64);
            int   oi1 = __shfl_xor(i1[r], off, 64);
            if (om1 < m1[r]) { m2[r] = fminf(m1[r], om2); m1[r] = om1; i1[r] = oi1; }
            else             { m2[r] = fminf(m2[r], om1); }
        }
    }
    if ((l & 15) == 0) {
        #pragma unroll
        for (int r = 0; r < 4; ++r) {
            int n = rowbase + w * 16 + kq * 4 + r;   // C row = kq*4 + r
            idx[n]  = i1[r];
            flag[n] = (m2[r] - m1[r] < MARGIN) ? 1 : 0;
        }
    }
}

// ---------------- k_rescan: exact f64 full-K re-rank of flagged rows ----------------
__global__ __launch_bounds__(256) void k_rescan(const float* __restrict__ Z,
                                                const float* __restrict__ E,
                                                const unsigned char* __restrict__ flag,
                                                int* __restrict__ idx) {
    __shared__ float  zrow[D_];
    __shared__ double wmin[4];
    __shared__ int    widx[4];
    int t = threadIdx.x, wave = t >> 6, l = t & 63;

    for (int n = blockIdx.x; n < N_; n += gridDim.x) {
        if (!flag[n]) continue;            // uniform across block
        int b = n >> 10, hw = n & (HW_ - 1);
        const float* zp = Z + (size_t)b * D_ * HW_ + hw;
        zrow[t] = zp[(size_t)t * HW_];
        __syncthreads();

        double bm = 1e300; int bi = 0;
        for (int kk = 0; kk < 256; ++kk) { // wave handles k in [wave*256, +256), ascending
            int k = (wave << 8) + kk;
            const float* er = E + (size_t)k * D_;
            double s = 0.0;
            #pragma unroll
            for (int q = 0; q < 4; ++q) {
                int d = l + q * 64;
                double dz = (double)zrow[d] - (double)er[d];
                s = fma(dz, dz, s);
            }
            #pragma unroll
            for (int off = 32; off; off >>= 1) s += __shfl_xor(s, off, 64);
            if (s < bm) { bm = s; bi = k; } // strict < : first (lowest k) wins ties
        }
        if (l == 0) { wmin[wave] = bm; widx[wave] = bi; }
        __syncthreads();
        if (t == 0) {
            double M = wmin[0]; int I = widx[0];
            #pragma unroll
            for (int w = 1; w < 4; ++w)
                if (wmin[w] < M) { M = wmin[w]; I = widx[w]; }
            idx[n] = I;
        }
        __syncthreads();
    }
}

// ---------------- k_gather: z_q output (NCHW), loss partials, counts ----------------
__global__ __launch_bounds__(256) void k_gather(const float* __restrict__ Z,
                                                const float* __restrict__ E,
                                                const int* __restrict__ idx,
                                                float* __restrict__ out_zq,
                                                int* __restrict__ counts,
                                                double* __restrict__ loss_acc) {
    __shared__ int    sidx[64];
    __shared__ double wls[4];
    int t = threadIdx.x;
    int rowbase = blockIdx.x * 64;
    int b = rowbase >> 10, hw0 = rowbase & (HW_ - 1);
    int l = t & 63, cq = t >> 6;

    if (t < 64) sidx[t] = idx[rowbase + t];
    __syncthreads();
    int i_l = sidx[l];

    const float* zb = Z      + (size_t)b * D_ * HW_ + hw0;
    float*       ob = out_zq + (size_t)b * D_ * HW_ + hw0;

    double ls = 0.0;
    for (int j = 0; j < 64; ++j) {
        int c = cq * 64 + j;
        float e = E[(size_t)i_l * D_ + c];          // gather (L2-hot, 1 MB table)
        float z = zb[(size_t)c * HW_ + l];          // coalesced
        ob[(size_t)c * HW_ + l] = e;                // coalesced
        double dz = (double)z - (double)e;
        ls = fma(dz, dz, ls);
    }
    #pragma unroll
    for (int off = 32; off; off >>= 1) ls += __shfl_xor(ls, off, 64);
    if (l == 0) wls[cq] = ls;
    __syncthreads();
    if (t == 0) atomicAdd(loss_acc, wls[0] + wls[1] + wls[2] + wls[3]);
    if (t < 64) atomicAdd(&counts[sidx[t]], 1);
}

// ---------------- k_final: loss & perplexity scalars ----------------
__global__ __launch_bounds__(256) void k_final(const int* __restrict__ counts,
                                               const double* __restrict__ loss_acc,
                                               float* __restrict__ out) {
    __shared__ double sh[256];
    int t = threadIdx.x;
    double s = 0.0;
    for (int k = t; k < K_; k += 256) {
        double p = (double)counts[k] / (double)N_;
        s += p * log(p + 1e-10);
    }
    sh[t] = s; __syncthreads();
    for (int off = 128; off; off >>= 1) {
        if (t < off) sh[t] += sh[t + off];
        __syncthreads();
    }
    if (t == 0) {
        out[0]       = (float)((*loss_acc) / (double)ND_ * 1.25);
        out[1 + ND_] = (float)exp(-sh[0]);
    }
}

extern "C" void kernel_launch(void* const* d_in, const int* in_sizes, int n_in,
                              void* d_out, int out_size, void* d_ws, size_t ws_size,
                              hipStream_t stream) {
    (void)in_sizes; (void)n_in; (void)out_size; (void)ws_size;
    const float* Z = (const float*)d_in[0];
    const float* E = (const float*)d_in[1];
    float* out = (float*)d_out;

    char* ws = (char*)d_ws;
    float*          e2f      = (float*)ws;                     // 4 KB
    int*            idx      = (int*)(ws + 4096);              // 256 KB
    unsigned char*  flag     = (unsigned char*)(ws + 266240);  // 64 KB
    int*            counts   = (int*)(ws + 331776);            // 4 KB
    double*         loss_acc = (double*)(ws + 335872);         // 8 B
    unsigned short* Ehi      = (unsigned short*)(ws + 339968); // 512 KB
    unsigned short* Elo      = (unsigned short*)(ws + 864256); // 512 KB

    k_init  <<<dim3(1024), dim3(256), 0, stream>>>(E, Ehi, Elo, e2f, counts, loss_acc);
    k_phase1<<<dim3(1024), dim3(256), 0, stream>>>(Z, Ehi, Elo, e2f, idx, flag);
    k_rescan<<<dim3(1024), dim3(256), 0, stream>>>(Z, E, flag, idx);
    k_gather<<<dim3(1024), dim3(256), 0, stream>>>(Z, E, idx, out + 1, counts, loss_acc);
    k_final <<<1,          dim3(256), 0, stream>>>(counts, loss_acc, out);
}

// Round 3
// 465.900 us; speedup vs baseline: 5.7565x; 5.3404x over previous
//
#include <hip/hip_runtime.h>

#define D_   256
#define HW_  1024
#define N_   65536
#define K_   1024
#define ND_  16777216
#define MARGIN 1e-4f
#define BM 128
#define BN 128

typedef __attribute__((ext_vector_type(8))) short bf16x8;
typedef __attribute__((ext_vector_type(4))) float f32x4;

__device__ inline unsigned short bf16_rne(float v) {
    unsigned u = __float_as_uint(v);
    return (unsigned short)((u + 0x7FFF + ((u >> 16) & 1)) >> 16);
}
__device__ inline float bf16_to_f(unsigned short h) {
    return __uint_as_float(((unsigned)h) << 16);
}

#define GLL16(g, l) __builtin_amdgcn_global_load_lds( \
    (const __attribute__((address_space(1))) unsigned int*)(const void*)(g), \
    (__attribute__((address_space(3))) unsigned int*)(void*)(l), 16, 0, 0)

// ---- k_init: E -> bf16 hi/lo + e2 (f64) + zero counts/nflag/loss ----
__global__ __launch_bounds__(256) void k_init(const float* __restrict__ E,
                                              unsigned short* __restrict__ Ehi,
                                              unsigned short* __restrict__ Elo,
                                              float* __restrict__ e2f,
                                              int* __restrict__ counts,
                                              int* __restrict__ nflag,
                                              double* __restrict__ loss_acc) {
    __shared__ double sh[256];
    int k = blockIdx.x, t = threadIdx.x;            // grid = 1024
    float v = E[(size_t)k * D_ + t];
    unsigned short h = bf16_rne(v);
    Ehi[(size_t)k * D_ + t] = h;
    Elo[(size_t)k * D_ + t] = bf16_rne(v - bf16_to_f(h));
    sh[t] = (double)v * v;
    __syncthreads();
    for (int off = 128; off; off >>= 1) {
        if (t < off) sh[t] += sh[t + off];
        __syncthreads();
    }
    if (t == 0) {
        e2f[k] = (float)sh[0];
        counts[k] = 0;
        if (k == 0) { *loss_acc = 0.0; *nflag = 0; }
    }
}

// ---- k_zsplit: Z [b][d][hw] fp32 -> Zhi/Zlo [n][d] bf16 (LDS transpose) ----
__global__ __launch_bounds__(256) void k_zsplit(const float* __restrict__ Z,
                                                unsigned short* __restrict__ Zhi,
                                                unsigned short* __restrict__ Zlo) {
    __shared__ unsigned short lh[32][264], ll[32][264];   // 264: 16B-aligned rows, bank-rotated
    int t = threadIdx.x;
    int bid = blockIdx.x;                 // 2048 = 64 b * 32 chunks
    int b = bid >> 5, hw0 = (bid & 31) * 32;
    int hw = t & 31, dq = t >> 5;         // dq 0..7
    const float* zb = Z + (size_t)b * (D_ * HW_) + hw0;
    #pragma unroll 8
    for (int j = 0; j < 32; ++j) {
        int d = j * 8 + dq;
        float v = zb[(size_t)d * HW_ + hw];
        unsigned short h = bf16_rne(v);
        lh[hw][d] = h;
        ll[hw][d] = bf16_rne(v - bf16_to_f(h));
    }
    __syncthreads();
    int row = t >> 3, cb = t & 7;         // row 0..31, chunk base 0..7
    size_t nbase = ((size_t)b * HW_ + hw0 + row) * D_;
    #pragma unroll
    for (int jj = 0; jj < 4; ++jj) {
        int ch = cb + jj * 8;             // 16B chunk 0..31
        *(bf16x8*)(Zhi + nbase + ch * 8) = *(const bf16x8*)&lh[row][ch * 8];
        *(bf16x8*)(Zlo + nbase + ch * 8) = *(const bf16x8*)&ll[row][ch * 8];
    }
}

// ---- k_phase1: 128x128 MFMA GEMM (split bf16 x3) + per-block top-2 partials ----
__global__ __launch_bounds__(256) void k_phase1(const unsigned short* __restrict__ Zhi,
                                                const unsigned short* __restrict__ Zlo,
                                                const unsigned short* __restrict__ Ehi,
                                                const unsigned short* __restrict__ Elo,
                                                const float* __restrict__ e2f,
                                                float* __restrict__ pm1,
                                                float* __restrict__ pm2,
                                                int* __restrict__ pi1) {
    __shared__ __align__(16) unsigned short lds[4 * 8192];  // Ah Al Bh Bl, each [128][64]
    int t = threadIdx.x, w = t >> 6, l = t & 63;
    int bid = blockIdx.x;
    int mb = bid >> 3, nb = bid & 7;       // n-fastest: 8 siblings share the A-tile (L3)
    int wr = w >> 1, wc = w & 1;

    const unsigned short* s0 = Zhi + (size_t)mb * BM * D_;
    const unsigned short* s1 = Zlo + (size_t)mb * BM * D_;
    const unsigned short* s2 = Ehi + (size_t)nb * BN * D_;
    const unsigned short* s3 = Elo + (size_t)nb * BN * D_;
    const unsigned short* mysrc = (w == 0) ? s0 : (w == 1) ? s1 : (w == 2) ? s2 : s3;
    unsigned short* myl = &lds[__builtin_amdgcn_readfirstlane(w * 8192)];

    int Rl = l >> 3;                       // row-within-8 for staging
    int lc = (l & 7) ^ (l >> 3);           // pre-swizzled source chunk (rule #21)

    f32x4 acc[4][4];
    #pragma unroll
    for (int m = 0; m < 4; ++m)
        #pragma unroll
        for (int nn = 0; nn < 4; ++nn) acc[m][nn] = (f32x4){0.f, 0.f, 0.f, 0.f};

    for (int kt = 0; kt < 4; ++kt) {
        #pragma unroll
        for (int i = 0; i < 16; ++i) {
            const unsigned short* g = mysrc + (size_t)(i * 8 + Rl) * D_ + kt * 64 + lc * 8;
            GLL16(g, myl + i * 512);
        }
        __syncthreads();
        int q = l >> 4;
        #pragma unroll
        for (int ks2 = 0; ks2 < 2; ++ks2) {
            int pcb = ((ks2 * 4 + q) ^ (l & 7)) * 16;  // swizzled chunk byte offset
            bf16x8 ah[4], al[4];
            #pragma unroll
            for (int m = 0; m < 4; ++m) {
                int off = (wr * 64 + m * 16 + (l & 15)) * 128 + pcb;
                ah[m] = *(const bf16x8*)((const char*)&lds[0]     + off);
                al[m] = *(const bf16x8*)((const char*)&lds[8192]  + off);
            }
            #pragma unroll
            for (int nn = 0; nn < 4; ++nn) {
                int offb = (wc * 64 + nn * 16 + (l & 15)) * 128 + pcb;
                bf16x8 bh = *(const bf16x8*)((const char*)&lds[16384] + offb);
                bf16x8 bl = *(const bf16x8*)((const char*)&lds[24576] + offb);
                #pragma unroll
                for (int m = 0; m < 4; ++m)
                    acc[m][nn] = __builtin_amdgcn_mfma_f32_16x16x32_bf16(ah[m], bh, acc[m][nn], 0, 0, 0);
                #pragma unroll
                for (int m = 0; m < 4; ++m)
                    acc[m][nn] = __builtin_amdgcn_mfma_f32_16x16x32_bf16(al[m], bh, acc[m][nn], 0, 0, 0);
                #pragma unroll
                for (int m = 0; m < 4; ++m)
                    acc[m][nn] = __builtin_amdgcn_mfma_f32_16x16x32_bf16(ah[m], bl, acc[m][nn], 0, 0, 0);
            }
        }
        __syncthreads();
    }

    // ---- epilogue: scores + per-row top-2 ----
    float m1v[4][4], m2v[4][4]; int i1v[4][4];   // [m][r]
    #pragma unroll
    for (int m = 0; m < 4; ++m)
        #pragma unroll
        for (int r = 0; r < 4; ++r) { m1v[m][r] = 3.4e38f; m2v[m][r] = 3.4e38f; i1v[m][r] = 0; }

    #pragma unroll
    for (int nn = 0; nn < 4; ++nn) {
        int c = nb * 128 + wc * 64 + nn * 16 + (l & 15);
        float e2 = e2f[c];
        #pragma unroll
        for (int m = 0; m < 4; ++m)
            #pragma unroll
            for (int r = 0; r < 4; ++r) {
                float s = fmaf(-2.f, acc[m][nn][r], e2);
                if (s < m1v[m][r])      { m2v[m][r] = m1v[m][r]; m1v[m][r] = s; i1v[m][r] = c; }
                else if (s < m2v[m][r]) { m2v[m][r] = s; }
            }
    }
    #pragma unroll
    for (int off = 1; off < 16; off <<= 1) {
        #pragma unroll
        for (int m = 0; m < 4; ++m)
            #pragma unroll
            for (int r = 0; r < 4; ++r) {
                float o1 = __shfl_xor(m1v[m][r], off, 64);
                float o2 = __shfl_xor(m2v[m][r], off, 64);
                int   oi = __shfl_xor(i1v[m][r], off, 64);
                if (o1 < m1v[m][r]) { m2v[m][r] = fminf(m1v[m][r], o2); m1v[m][r] = o1; i1v[m][r] = oi; }
                else                { m2v[m][r] = fminf(m2v[m][r], o1); }
            }
    }
    __syncthreads();                       // reuse lds as exchange
    float* ex1 = (float*)lds;              // [4 waves][64 rows]
    float* ex2 = ex1 + 256;
    int*   exi = (int*)(ex2 + 256);
    if ((l & 15) == 0) {
        int q = l >> 4;
        #pragma unroll
        for (int m = 0; m < 4; ++m)
            #pragma unroll
            for (int r = 0; r < 4; ++r) {
                int e = (wr * 2 + wc) * 64 + m * 16 + q * 4 + r;
                ex1[e] = m1v[m][r]; ex2[e] = m2v[m][r]; exi[e] = i1v[m][r];
            }
    }
    __syncthreads();
    if (t < 128) {
        int wr2 = t >> 6, rw = t & 63;
        int e0 = (wr2 * 2 + 0) * 64 + rw, e1 = (wr2 * 2 + 1) * 64 + rw;
        float a1 = ex1[e0], a2 = ex2[e0]; int ai = exi[e0];
        float b1 = ex1[e1], b2 = ex2[e1]; int bi = exi[e1];
        float M1, M2; int I1;
        if (a1 <= b1) { M1 = a1; I1 = ai; M2 = fminf(a2, b1); }
        else          { M1 = b1; I1 = bi; M2 = fminf(b2, a1); }
        size_t p = (size_t)nb * N_ + (size_t)mb * 128 + t;
        pm1[p] = M1; pm2[p] = M2; pi1[p] = I1;
    }
}

// ---- k_merge: fold 8 partials -> idx, counts, compacted flag list ----
__global__ __launch_bounds__(256) void k_merge(const float* __restrict__ pm1,
                                               const float* __restrict__ pm2,
                                               const int* __restrict__ pi1,
                                               int* __restrict__ idx,
                                               int* __restrict__ counts,
                                               int* __restrict__ list,
                                               int* __restrict__ nflag) {
    int n = blockIdx.x * 256 + threadIdx.x;     // grid = 256
    float M1 = 3.4e38f, M2 = 3.4e38f; int I1 = 0;
    #pragma unroll
    for (int nb = 0; nb < 8; ++nb) {
        size_t p = (size_t)nb * N_ + n;
        float a1 = pm1[p], a2 = pm2[p]; int ai = pi1[p];
        if (a1 < M1) { M2 = fminf(M1, a2); M1 = a1; I1 = ai; }
        else         { M2 = fminf(M2, a1); }
    }
    idx[n] = I1;
    atomicAdd(&counts[I1], 1);
    bool fl = (M2 - M1) < MARGIN;
    unsigned long long mask = __ballot(fl);
    int lane = threadIdx.x & 63;
    int cnt = __popcll(mask);
    if (cnt) {
        int base = 0;
        if (lane == 0) base = atomicAdd(nflag, cnt);
        base = __shfl(base, 0, 64);
        if (fl) {
            int pos = __popcll(mask & ((1ull << lane) - 1ull));
            list[base + pos] = n;
        }
    }
}

// ---- k_rescan: exact f64 full-K re-rank of listed rows (+counts fixup) ----
__global__ __launch_bounds__(256) void k_rescan(const float* __restrict__ Z,
                                                const float* __restrict__ E,
                                                const int* __restrict__ list,
                                                const int* __restrict__ nflag,
                                                int* __restrict__ idx,
                                                int* __restrict__ counts) {
    __shared__ float zrow[D_];
    __shared__ double wmin[4];
    __shared__ int    widx[4];
    int t = threadIdx.x, wave = t >> 6, l = t & 63;
    int nf = *nflag;
    for (int ii = blockIdx.x; ii < nf; ii += 1024) {    // grid = 1024
        int n = list[ii];
        int b = n >> 10, hw = n & (HW_ - 1);
        zrow[t] = Z[(size_t)b * (D_ * HW_) + (size_t)t * HW_ + hw];
        __syncthreads();
        double bm = 1e300; int bi = 0;
        for (int kk = 0; kk < 256; ++kk) {              // ascending k: first index wins ties
            int k = (wave << 8) + kk;
            const float* er = E + (size_t)k * D_;
            double s = 0.0;
            #pragma unroll
            for (int qd = 0; qd < 4; ++qd) {
                int d = l + qd * 64;
                double dz = (double)zrow[d] - (double)er[d];
                s = fma(dz, dz, s);
            }
            #pragma unroll
            for (int off = 32; off; off >>= 1) s += __shfl_xor(s, off, 64);
            if (s < bm) { bm = s; bi = k; }
        }
        if (l == 0) { wmin[wave] = bm; widx[wave] = bi; }
        __syncthreads();
        if (t == 0) {
            double M = wmin[0]; int I = widx[0];
            #pragma unroll
            for (int ww = 1; ww < 4; ++ww)
                if (wmin[ww] < M) { M = wmin[ww]; I = widx[ww]; }
            int old = idx[n];
            if (I != old) {
                idx[n] = I;
                atomicSub(&counts[old], 1);
                atomicAdd(&counts[I], 1);
            }
        }
        __syncthreads();
    }
}

// ---- k_gather: z_q out (NCHW) via LDS-staged e-rows + f64 loss ----
__global__ __launch_bounds__(256) void k_gather(const float* __restrict__ Z,
                                                const float* __restrict__ E,
                                                const int* __restrict__ idx,
                                                float* __restrict__ out_zq,
                                                double* __restrict__ loss_acc) {
    __shared__ float ecache[32][257];
    __shared__ int sidx[32];
    __shared__ double wls[4];
    int t = threadIdx.x;
    int n0 = blockIdx.x * 32;                 // grid = 2048
    int b = n0 >> 10, hw0 = n0 & (HW_ - 1);
    if (t < 32) sidx[t] = idx[n0 + t];
    __syncthreads();
    #pragma unroll 8
    for (int j = 0; j < 32; ++j)
        ecache[j][t] = E[(size_t)sidx[j] * D_ + t];   // coalesced 1KB row loads
    __syncthreads();
    int hw = t & 31, cq = t >> 5;
    const float* zb = Z      + (size_t)b * (D_ * HW_) + hw0 + hw;
    float*       ob = out_zq + (size_t)b * (D_ * HW_) + hw0 + hw;
    double ls = 0.0;
    #pragma unroll 4
    for (int jj = 0; jj < 32; ++jj) {
        int c = cq * 32 + jj;
        float e = ecache[hw][c];
        float z = zb[(size_t)c * HW_];
        ob[(size_t)c * HW_] = e;
        double dz = (double)z - (double)e;
        ls = fma(dz, dz, ls);
    }
    #pragma unroll
    for (int off = 32; off; off >>= 1) ls += __shfl_xor(ls, off, 64);
    int wv = t >> 6;
    if ((t & 63) == 0) wls[wv] = ls;
    __syncthreads();
    if (t == 0) atomicAdd(loss_acc, wls[0] + wls[1] + wls[2] + wls[3]);
}

// ---- k_final ----
__global__ __launch_bounds__(256) void k_final(const int* __restrict__ counts,
                                               const double* __restrict__ loss_acc,
                                               float* __restrict__ out) {
    __shared__ double sh[256];
    int t = threadIdx.x;
    double s = 0.0;
    for (int k = t; k < K_; k += 256) {
        double p = (double)counts[k] / (double)N_;
        s += p * log(p + 1e-10);
    }
    sh[t] = s; __syncthreads();
    for (int off = 128; off; off >>= 1) {
        if (t < off) sh[t] += sh[t + off];
        __syncthreads();
    }
    if (t == 0) {
        out[0]       = (float)((*loss_acc) / (double)ND_ * 1.25);
        out[1 + ND_] = (float)exp(-sh[0]);
    }
}

extern "C" void kernel_launch(void* const* d_in, const int* in_sizes, int n_in,
                              void* d_out, int out_size, void* d_ws, size_t ws_size,
                              hipStream_t stream) {
    (void)in_sizes; (void)n_in; (void)out_size; (void)ws_size;
    const float* Z = (const float*)d_in[0];
    const float* E = (const float*)d_in[1];
    float* out = (float*)d_out;

    char* ws = (char*)d_ws;
    unsigned short* Zhi      = (unsigned short*)(ws);                 // 32 MB
    unsigned short* Zlo      = (unsigned short*)(ws + 33554432);      // 32 MB
    unsigned short* Ehi      = (unsigned short*)(ws + 67108864);      // 512 KB
    unsigned short* Elo      = (unsigned short*)(ws + 67633152);      // 512 KB
    float*          e2f      = (float*)(ws + 68157440);               // 4 KB
    float*          pm1      = (float*)(ws + 68161536);               // 2 MB
    float*          pm2      = (float*)(ws + 70258688);               // 2 MB
    int*            pi1      = (int*)  (ws + 72355840);               // 2 MB
    int*            idx      = (int*)  (ws + 74452992);               // 256 KB
    int*            list     = (int*)  (ws + 74715136);               // 256 KB
    int*            counts   = (int*)  (ws + 74977280);               // 4 KB
    int*            nflag    = (int*)  (ws + 74981376);               // 64 B
    double*         loss_acc = (double*)(ws + 74981440);              // 8 B

    k_init  <<<dim3(1024), dim3(256), 0, stream>>>(E, Ehi, Elo, e2f, counts, nflag, loss_acc);
    k_zsplit<<<dim3(2048), dim3(256), 0, stream>>>(Z, Zhi, Zlo);
    k_phase1<<<dim3(4096), dim3(256), 0, stream>>>(Zhi, Zlo, Ehi, Elo, e2f, pm1, pm2, pi1);
    k_merge <<<dim3(256),  dim3(256), 0, stream>>>(pm1, pm2, pi1, idx, counts, list, nflag);
    k_rescan<<<dim3(1024), dim3(256), 0, stream>>>(Z, E, list, nflag, idx, counts);
    k_gather<<<dim3(2048), dim3(256), 0, stream>>>(Z, E, idx, out + 1, loss_acc);
    k_final <<<1,          dim3(256), 0, stream>>>(counts, loss_acc, out);
}

// Round 4
// 402.047 us; speedup vs baseline: 6.6708x; 1.1588x over previous
//
#include <hip/hip_runtime.h>

#define D_   256
#define HW_  1024
#define N_   65536
#define K_   1024
#define ND_  16777216
// worst-case fp16 phase1 score error: S1*2^-19*1.03 + flush/accum slack
#define MARGIN_A 2.2e-6f
#define MARGIN_B 6.0e-5f

typedef __attribute__((ext_vector_type(8))) short bf16x8;
typedef __attribute__((ext_vector_type(8))) _Float16 f16x8;
typedef __attribute__((ext_vector_type(4))) float f32x4;

union f16cv { _Float16 h; unsigned short u; };

__device__ inline unsigned short f16_bits(float v) {
    f16cv c; c.h = (_Float16)v; return c.u;
}

#define GLL16(g, l) __builtin_amdgcn_global_load_lds( \
    (const __attribute__((address_space(1))) unsigned int*)(const void*)(g), \
    (__attribute__((address_space(3))) unsigned int*)(void*)(l), 16, 0, 0)

// ---- k_init: E -> f16 (x1024) + Et (f32 transpose) + e2 (f32/f64) + zeros ----
__global__ __launch_bounds__(256) void k_init(const float* __restrict__ E,
                                              unsigned short* __restrict__ Eh,
                                              float* __restrict__ Et,
                                              float* __restrict__ e2f,
                                              double* __restrict__ e2d,
                                              int* __restrict__ counts,
                                              int* __restrict__ nflag,
                                              double* __restrict__ loss_acc) {
    __shared__ double sh[256];
    int k = blockIdx.x, t = threadIdx.x;            // grid = 1024
    float v = E[(size_t)k * D_ + t];
    Eh[(size_t)k * D_ + t] = f16_bits(v * 1024.f);  // exact pow2 scale
    Et[(size_t)t * K_ + k] = v;
    sh[t] = (double)v * v;
    __syncthreads();
    for (int off = 128; off; off >>= 1) {
        if (t < off) sh[t] += sh[t + off];
        __syncthreads();
    }
    if (t == 0) {
        e2f[k] = (float)sh[0];
        e2d[k] = sh[0];
        counts[k] = 0;
        if (k == 0) { *loss_acc = 0.0; *nflag = 0; }
    }
}

// ---- k_zsplit: Z [b][d][hw] fp32 -> Zh [n][d] f16 + S1[n] = sum|z_d| ----
__global__ __launch_bounds__(256) void k_zsplit(const float* __restrict__ Z,
                                                unsigned short* __restrict__ Zh,
                                                float* __restrict__ S1) {
    __shared__ unsigned short lh[32][264];
    __shared__ float sabs[32][8];
    int t = threadIdx.x;
    int bid = blockIdx.x;                 // 2048 = 64 b * 32 chunks
    int b = bid >> 5, hw0 = (bid & 31) * 32;
    int hw = t & 31, dq = t >> 5;         // dq 0..7
    const float* zb = Z + (size_t)b * (D_ * HW_) + hw0;
    float asum = 0.f;
    #pragma unroll 8
    for (int j = 0; j < 32; ++j) {
        int d = j * 8 + dq;
        float v = zb[(size_t)d * HW_ + hw];
        lh[hw][d] = f16_bits(v);
        asum += fabsf(v);
    }
    sabs[hw][dq] = asum;
    __syncthreads();
    int row = t >> 3, cb = t & 7;
    size_t nbase = ((size_t)b * HW_ + hw0 + row) * D_;
    #pragma unroll
    for (int jj = 0; jj < 4; ++jj) {
        int ch = cb + jj * 8;
        *(bf16x8*)(Zh + nbase + ch * 8) = *(const bf16x8*)&lh[row][ch * 8];
    }
    if (t < 32) {
        float s = 0.f;
        #pragma unroll
        for (int q = 0; q < 8; ++q) s += sabs[t][q];
        S1[(size_t)b * HW_ + hw0 + t] = s;
    }
}

// ---- k_phase1: 128x128 f16 MFMA GEMM + per-block top-2 partials ----
__global__ __launch_bounds__(256) void k_phase1(const unsigned short* __restrict__ Zh,
                                                const unsigned short* __restrict__ Eh,
                                                const float* __restrict__ e2f,
                                                float* __restrict__ pm1,
                                                float* __restrict__ pm2,
                                                int* __restrict__ pi1) {
    __shared__ __align__(16) unsigned short lds[2 * 8192];  // A [128][64], B [128][64]
    int t = threadIdx.x, w = t >> 6, l = t & 63;
    int bid = blockIdx.x;
    int mb = bid >> 3, nb = bid & 7;       // n-fastest: 8 siblings share A-tile
    int wr = w >> 1, wc = w & 1;

    const unsigned short* src =
        (w < 2 ? Zh + (size_t)mb * 128 * D_ : Eh + (size_t)nb * 128 * D_)
        + (size_t)(w & 1) * 64 * D_;
    unsigned short* myl = &lds[__builtin_amdgcn_readfirstlane((w >> 1) * 8192 + (w & 1) * 4096)];

    int Rl = l >> 3;
    int lc = (l & 7) ^ (l >> 3);           // pre-swizzled source chunk (rule #21)

    f32x4 acc[4][4];
    #pragma unroll
    for (int m = 0; m < 4; ++m)
        #pragma unroll
        for (int nn = 0; nn < 4; ++nn) acc[m][nn] = (f32x4){0.f, 0.f, 0.f, 0.f};

    for (int kt = 0; kt < 4; ++kt) {
        #pragma unroll
        for (int i = 0; i < 8; ++i) {
            const unsigned short* g = src + (size_t)(i * 8 + Rl) * D_ + kt * 64 + lc * 8;
            GLL16(g, myl + i * 512);
        }
        __syncthreads();
        int q = l >> 4;
        #pragma unroll
        for (int ks2 = 0; ks2 < 2; ++ks2) {
            int pcb = ((ks2 * 4 + q) ^ (l & 7)) * 16;  // swizzled chunk byte offset
            f16x8 ah[4];
            #pragma unroll
            for (int m = 0; m < 4; ++m)
                ah[m] = *(const f16x8*)((const char*)&lds[0] + (wr * 64 + m * 16 + (l & 15)) * 128 + pcb);
            #pragma unroll
            for (int nn = 0; nn < 4; ++nn) {
                f16x8 bh = *(const f16x8*)((const char*)&lds[8192] + (wc * 64 + nn * 16 + (l & 15)) * 128 + pcb);
                #pragma unroll
                for (int m = 0; m < 4; ++m)
                    acc[m][nn] = __builtin_amdgcn_mfma_f32_16x16x32_f16(ah[m], bh, acc[m][nn], 0, 0, 0);
            }
        }
        __syncthreads();
    }

    // ---- epilogue: scores + per-row top-2 ----
    float m1v[4][4], m2v[4][4]; int i1v[4][4];   // [m][r]
    #pragma unroll
    for (int m = 0; m < 4; ++m)
        #pragma unroll
        for (int r = 0; r < 4; ++r) { m1v[m][r] = 3.4e38f; m2v[m][r] = 3.4e38f; i1v[m][r] = 0; }

    #pragma unroll
    for (int nn = 0; nn < 4; ++nn) {
        int c = nb * 128 + wc * 64 + nn * 16 + (l & 15);
        float e2 = e2f[c];
        #pragma unroll
        for (int m = 0; m < 4; ++m)
            #pragma unroll
            for (int r = 0; r < 4; ++r) {
                float s = fmaf(-2.f / 1024.f, acc[m][nn][r], e2);   // unscale dot
                if (s < m1v[m][r])      { m2v[m][r] = m1v[m][r]; m1v[m][r] = s; i1v[m][r] = c; }
                else if (s < m2v[m][r]) { m2v[m][r] = s; }
            }
    }
    #pragma unroll
    for (int off = 1; off < 16; off <<= 1) {
        #pragma unroll
        for (int m = 0; m < 4; ++m)
            #pragma unroll
            for (int r = 0; r < 4; ++r) {
                float o1 = __shfl_xor(m1v[m][r], off, 64);
                float o2 = __shfl_xor(m2v[m][r], off, 64);
                int   oi = __shfl_xor(i1v[m][r], off, 64);
                if (o1 < m1v[m][r]) { m2v[m][r] = fminf(m1v[m][r], o2); m1v[m][r] = o1; i1v[m][r] = oi; }
                else                { m2v[m][r] = fminf(m2v[m][r], o1); }
            }
    }
    __syncthreads();                       // reuse lds as exchange
    float* ex1 = (float*)lds;              // [4 waves][64 rows]
    float* ex2 = ex1 + 256;
    int*   exi = (int*)(ex2 + 256);
    if ((l & 15) == 0) {
        int q = l >> 4;
        #pragma unroll
        for (int m = 0; m < 4; ++m)
            #pragma unroll
            for (int r = 0; r < 4; ++r) {
                int e = (wr * 2 + wc) * 64 + m * 16 + q * 4 + r;
                ex1[e] = m1v[m][r]; ex2[e] = m2v[m][r]; exi[e] = i1v[m][r];
            }
    }
    __syncthreads();
    if (t < 128) {
        int wr2 = t >> 6, rw = t & 63;
        int e0 = (wr2 * 2 + 0) * 64 + rw, e1 = (wr2 * 2 + 1) * 64 + rw;
        float a1 = ex1[e0], a2 = ex2[e0]; int ai = exi[e0];
        float b1 = ex1[e1], b2 = ex2[e1]; int bi = exi[e1];
        float M1, M2; int I1;
        if (a1 <= b1) { M1 = a1; I1 = ai; M2 = fminf(a2, b1); }
        else          { M1 = b1; I1 = bi; M2 = fminf(b2, a1); }
        size_t p = (size_t)nb * N_ + (size_t)mb * 128 + t;
        pm1[p] = M1; pm2[p] = M2; pi1[p] = I1;
    }
}

// ---- k_merge: fold 8 partials -> idx, counts, compacted flag list (S1 margin) ----
__global__ __launch_bounds__(256) void k_merge(const float* __restrict__ pm1,
                                               const float* __restrict__ pm2,
                                               const int* __restrict__ pi1,
                                               const float* __restrict__ S1,
                                               int* __restrict__ idx,
                                               int* __restrict__ counts,
                                               int* __restrict__ list,
                                               int* __restrict__ nflag) {
    int n = blockIdx.x * 256 + threadIdx.x;     // grid = 256
    float M1 = 3.4e38f, M2 = 3.4e38f; int I1 = 0;
    #pragma unroll
    for (int nb = 0; nb < 8; ++nb) {
        size_t p = (size_t)nb * N_ + n;
        float a1 = pm1[p], a2 = pm2[p]; int ai = pi1[p];
        if (a1 < M1) { M2 = fminf(M1, a2); M1 = a1; I1 = ai; }
        else         { M2 = fminf(M2, a1); }
    }
    idx[n] = I1;
    atomicAdd(&counts[I1], 1);
    bool fl = (M2 - M1) < fmaf(S1[n], MARGIN_A, MARGIN_B);
    unsigned long long mask = __ballot(fl);
    int lane = threadIdx.x & 63;
    int cnt = __popcll(mask);
    if (cnt) {
        int base = 0;
        if (lane == 0) base = atomicAdd(nflag, cnt);
        base = __shfl(base, 0, 64);
        if (fl) {
            int pos = __popcll(mask & ((1ull << lane) - 1ull));
            list[base + pos] = n;
        }
    }
}

// ---- k_rescan: exact f64 re-rank, lane-per-code (no inner cross-lane reduce) ----
__global__ __launch_bounds__(256) void k_rescan(const float* __restrict__ Z,
                                                const float* __restrict__ Et,
                                                const double* __restrict__ e2d,
                                                const int* __restrict__ list,
                                                const int* __restrict__ nflag,
                                                int* __restrict__ idx,
                                                int* __restrict__ counts) {
    __shared__ float  zs[256];
    __shared__ double rv[256];
    __shared__ int    ri[256];
    int t = threadIdx.x;
    int nf = *nflag;
    for (int ii = blockIdx.x; ii < nf; ii += 4096) {     // grid = 4096
        int n = list[ii];
        int b = n >> 10, hw = n & (HW_ - 1);
        zs[t] = Z[(size_t)b * (D_ * HW_) + (size_t)t * HW_ + hw];
        __syncthreads();
        rv[t] = (double)zs[t] * (double)zs[t];
        __syncthreads();
        for (int off = 128; off; off >>= 1) {
            if (t < off) rv[t] += rv[t + off];
            __syncthreads();
        }
        double z2 = rv[0];
        __syncthreads();                                 // all read before rv reuse

        double s0 = 0.0, s1 = 0.0, s2 = 0.0, s3 = 0.0;
        #pragma unroll 4
        for (int d = 0; d < 256; ++d) {
            double zv = (double)zs[d];                   // LDS broadcast
            float4 e4 = *(const float4*)(Et + (size_t)d * K_ + 4 * t);
            s0 = fma(zv, (double)e4.x, s0);
            s1 = fma(zv, (double)e4.y, s1);
            s2 = fma(zv, (double)e4.z, s2);
            s3 = fma(zv, (double)e4.w, s3);
        }
        double best = 1e300; int bi = 0;
        double dv[4] = { fma(-2.0, s0, z2 + e2d[4 * t + 0]),
                         fma(-2.0, s1, z2 + e2d[4 * t + 1]),
                         fma(-2.0, s2, z2 + e2d[4 * t + 2]),
                         fma(-2.0, s3, z2 + e2d[4 * t + 3]) };
        #pragma unroll
        for (int c = 0; c < 4; ++c)
            if (dv[c] < best) { best = dv[c]; bi = 4 * t + c; }  // ascending c: first wins
        rv[t] = best; ri[t] = bi;
        __syncthreads();
        for (int off = 128; off; off >>= 1) {
            if (t < off) {
                double ov = rv[t + off]; int oi = ri[t + off];
                if (ov < rv[t] || (ov == rv[t] && oi < ri[t])) { rv[t] = ov; ri[t] = oi; }
            }
            __syncthreads();
        }
        if (t == 0) {
            int I = ri[0], old = idx[n];
            if (I != old) {
                idx[n] = I;
                atomicSub(&counts[old], 1);
                atomicAdd(&counts[I], 1);
            }
        }
        __syncthreads();
    }
}

// ---- k_gather: z_q out (NCHW) via LDS-staged e-rows + f64 loss ----
__global__ __launch_bounds__(256) void k_gather(const float* __restrict__ Z,
                                                const float* __restrict__ E,
                                                const int* __restrict__ idx,
                                                float* __restrict__ out_zq,
                                                double* __restrict__ loss_acc) {
    __shared__ float ecache[32][257];
    __shared__ int sidx[32];
    __shared__ double wls[4];
    int t = threadIdx.x;
    int n0 = blockIdx.x * 32;                 // grid = 2048
    int b = n0 >> 10, hw0 = n0 & (HW_ - 1);
    if (t < 32) sidx[t] = idx[n0 + t];
    __syncthreads();
    #pragma unroll 8
    for (int j = 0; j < 32; ++j)
        ecache[j][t] = E[(size_t)sidx[j] * D_ + t];
    __syncthreads();
    int hw = t & 31, cq = t >> 5;
    const float* zb = Z      + (size_t)b * (D_ * HW_) + hw0 + hw;
    float*       ob = out_zq + (size_t)b * (D_ * HW_) + hw0 + hw;
    double ls = 0.0;
    #pragma unroll 4
    for (int jj = 0; jj < 32; ++jj) {
        int c = cq * 32 + jj;
        float e = ecache[hw][c];
        float z = zb[(size_t)c * HW_];
        ob[(size_t)c * HW_] = e;
        double dz = (double)z - (double)e;
        ls = fma(dz, dz, ls);
    }
    #pragma unroll
    for (int off = 32; off; off >>= 1) ls += __shfl_xor(ls, off, 64);
    int wv = t >> 6;
    if ((t & 63) == 0) wls[wv] = ls;
    __syncthreads();
    if (t == 0) atomicAdd(loss_acc, wls[0] + wls[1] + wls[2] + wls[3]);
}

// ---- k_final ----
__global__ __launch_bounds__(256) void k_final(const int* __restrict__ counts,
                                               const double* __restrict__ loss_acc,
                                               float* __restrict__ out) {
    __shared__ double sh[256];
    int t = threadIdx.x;
    double s = 0.0;
    for (int k = t; k < K_; k += 256) {
        double p = (double)counts[k] / (double)N_;
        s += p * log(p + 1e-10);
    }
    sh[t] = s; __syncthreads();
    for (int off = 128; off; off >>= 1) {
        if (t < off) sh[t] += sh[t + off];
        __syncthreads();
    }
    if (t == 0) {
        out[0]       = (float)((*loss_acc) / (double)ND_ * 1.25);
        out[1 + ND_] = (float)exp(-sh[0]);
    }
}

extern "C" void kernel_launch(void* const* d_in, const int* in_sizes, int n_in,
                              void* d_out, int out_size, void* d_ws, size_t ws_size,
                              hipStream_t stream) {
    (void)in_sizes; (void)n_in; (void)out_size; (void)ws_size;
    const float* Z = (const float*)d_in[0];
    const float* E = (const float*)d_in[1];
    float* out = (float*)d_out;

    char* ws = (char*)d_ws;
    unsigned short* Zh       = (unsigned short*)(ws);              // 32 MB
    unsigned short* Eh       = (unsigned short*)(ws + 33554432);   // 512 KB
    float*          Et       = (float*)(ws + 34078720);            // 1 MB
    float*          e2f      = (float*)(ws + 35127296);            // 4 KB
    double*         e2d      = (double*)(ws + 35131392);           // 8 KB
    float*          S1       = (float*)(ws + 35139584);            // 256 KB
    float*          pm1      = (float*)(ws + 35401728);            // 2 MB
    float*          pm2      = (float*)(ws + 37498880);            // 2 MB
    int*            pi1      = (int*)  (ws + 39596032);            // 2 MB
    int*            idx      = (int*)  (ws + 41693184);            // 256 KB
    int*            list     = (int*)  (ws + 41955328);            // 256 KB
    int*            counts   = (int*)  (ws + 42217472);            // 4 KB
    int*            nflag    = (int*)  (ws + 42221568);            // 64 B
    double*         loss_acc = (double*)(ws + 42221632);           // 8 B

    k_init  <<<dim3(1024), dim3(256), 0, stream>>>(E, Eh, Et, e2f, e2d, counts, nflag, loss_acc);
    k_zsplit<<<dim3(2048), dim3(256), 0, stream>>>(Z, Zh, S1);
    k_phase1<<<dim3(4096), dim3(256), 0, stream>>>(Zh, Eh, e2f, pm1, pm2, pi1);
    k_merge <<<dim3(256),  dim3(256), 0, stream>>>(pm1, pm2, pi1, S1, idx, counts, list, nflag);
    k_rescan<<<dim3(4096), dim3(256), 0, stream>>>(Z, Et, e2d, list, nflag, idx, counts);
    k_gather<<<dim3(2048), dim3(256), 0, stream>>>(Z, E, idx, out + 1, loss_acc);
    k_final <<<1,          dim3(256), 0, stream>>>(counts, loss_acc, out);
}

// Round 5
// 391.155 us; speedup vs baseline: 6.8565x; 1.0278x over previous
//
#include <hip/hip_runtime.h>

#define D_   256
#define HW_  1024
#define N_   65536
#define K_   1024
#define ND_  16777216
// one-sided fp16 phase1 score error bound: S1*A + B (conservative ~2x)
#define MARGIN_A 2.2e-6f
#define MARGIN_B 6.0e-5f

typedef __attribute__((ext_vector_type(8))) short bf16x8;
typedef __attribute__((ext_vector_type(8))) _Float16 f16x8;
typedef __attribute__((ext_vector_type(4))) float f32x4;

union f16cv { _Float16 h; unsigned short u; };

__device__ inline unsigned short f16_bits(float v) {
    f16cv c; c.h = (_Float16)v; return c.u;
}

__device__ inline void ins4(float v, int i,
                            float& r0, int& q0, float& r1, int& q1,
                            float& r2, int& q2, float& r3, int& q3) {
    if (v < r0 || (v == r0 && i < q0)) { r3=r2;q3=q2; r2=r1;q2=q1; r1=r0;q1=q0; r0=v;q0=i; }
    else if (v < r1 || (v == r1 && i < q1)) { r3=r2;q3=q2; r2=r1;q2=q1; r1=v;q1=i; }
    else if (v < r2 || (v == r2 && i < q2)) { r3=r2;q3=q2; r2=v;q2=i; }
    else if (v < r3 || (v == r3 && i < q3)) { r3=v;q3=i; }
}

#define GLL16(g, l) __builtin_amdgcn_global_load_lds( \
    (const __attribute__((address_space(1))) unsigned int*)(const void*)(g), \
    (__attribute__((address_space(3))) unsigned int*)(void*)(l), 16, 0, 0)

// ---- k_init: E -> f16 (x1024) + Et (f32 transpose) + e2 (f32/f64) + zeros ----
__global__ __launch_bounds__(256) void k_init(const float* __restrict__ E,
                                              unsigned short* __restrict__ Eh,
                                              float* __restrict__ Et,
                                              float* __restrict__ e2f,
                                              double* __restrict__ e2d,
                                              int* __restrict__ counts,
                                              int* __restrict__ nflag2,
                                              double* __restrict__ loss_acc) {
    __shared__ double sh[256];
    int k = blockIdx.x, t = threadIdx.x;            // grid = 1024
    float v = E[(size_t)k * D_ + t];
    Eh[(size_t)k * D_ + t] = f16_bits(v * 1024.f);  // exact pow2 scale
    Et[(size_t)t * K_ + k] = v;
    sh[t] = (double)v * v;
    __syncthreads();
    for (int off = 128; off; off >>= 1) {
        if (t < off) sh[t] += sh[t + off];
        __syncthreads();
    }
    if (t == 0) {
        e2f[k] = (float)sh[0];
        e2d[k] = sh[0];
        counts[k] = 0;
        if (k == 0) { *loss_acc = 0.0; *nflag2 = 0; }
    }
}

// ---- k_zsplit: Z [b][d][hw] fp32 -> Zh [n][d] f16 + S1[n] = sum|z_d| ----
__global__ __launch_bounds__(256) void k_zsplit(const float* __restrict__ Z,
                                                unsigned short* __restrict__ Zh,
                                                float* __restrict__ S1) {
    __shared__ unsigned short lh[32][264];
    __shared__ float sabs[32][8];
    int t = threadIdx.x;
    int bid = blockIdx.x;                 // 2048 = 64 b * 32 chunks
    int b = bid >> 5, hw0 = (bid & 31) * 32;
    int hw = t & 31, dq = t >> 5;         // dq 0..7
    const float* zb = Z + (size_t)b * (D_ * HW_) + hw0;
    float asum = 0.f;
    #pragma unroll 8
    for (int j = 0; j < 32; ++j) {
        int d = j * 8 + dq;
        float v = zb[(size_t)d * HW_ + hw];
        lh[hw][d] = f16_bits(v);
        asum += fabsf(v);
    }
    sabs[hw][dq] = asum;
    __syncthreads();
    int row = t >> 3, cb = t & 7;
    size_t nbase = ((size_t)b * HW_ + hw0 + row) * D_;
    #pragma unroll
    for (int jj = 0; jj < 4; ++jj) {
        int ch = cb + jj * 8;
        *(bf16x8*)(Zh + nbase + ch * 8) = *(const bf16x8*)&lh[row][ch * 8];
    }
    if (t < 32) {
        float s = 0.f;
        #pragma unroll
        for (int q = 0; q < 8; ++q) s += sabs[t][q];
        S1[(size_t)b * HW_ + hw0 + t] = s;
    }
}

// ---- k_phase1: 128x128 f16 MFMA GEMM + per-block top-4 partials ----
__global__ __launch_bounds__(256) void k_phase1(const unsigned short* __restrict__ Zh,
                                                const unsigned short* __restrict__ Eh,
                                                const float* __restrict__ e2f,
                                                float4* __restrict__ pv,
                                                int4* __restrict__ pi) {
    __shared__ __align__(16) unsigned short lds[2 * 8192];  // A [128][64], B [128][64]
    int t = threadIdx.x, w = t >> 6, l = t & 63;
    int bid = blockIdx.x;
    int mb = bid >> 3, nb = bid & 7;       // n-fastest: 8 siblings share A-tile
    int wr = w >> 1, wc = w & 1;

    const unsigned short* src =
        (w < 2 ? Zh + (size_t)mb * 128 * D_ : Eh + (size_t)nb * 128 * D_)
        + (size_t)(w & 1) * 64 * D_;
    unsigned short* myl = &lds[__builtin_amdgcn_readfirstlane((w >> 1) * 8192 + (w & 1) * 4096)];

    int Rl = l >> 3;
    int lc = (l & 7) ^ (l >> 3);           // pre-swizzled source chunk (rule #21)

    f32x4 acc[4][4];
    #pragma unroll
    for (int m = 0; m < 4; ++m)
        #pragma unroll
        for (int nn = 0; nn < 4; ++nn) acc[m][nn] = (f32x4){0.f, 0.f, 0.f, 0.f};

    for (int kt = 0; kt < 4; ++kt) {
        #pragma unroll
        for (int i = 0; i < 8; ++i) {
            const unsigned short* g = src + (size_t)(i * 8 + Rl) * D_ + kt * 64 + lc * 8;
            GLL16(g, myl + i * 512);
        }
        __syncthreads();
        int q = l >> 4;
        #pragma unroll
        for (int ks2 = 0; ks2 < 2; ++ks2) {
            int pcb = ((ks2 * 4 + q) ^ (l & 7)) * 16;  // swizzled chunk byte offset
            f16x8 ah[4];
            #pragma unroll
            for (int m = 0; m < 4; ++m)
                ah[m] = *(const f16x8*)((const char*)&lds[0] + (wr * 64 + m * 16 + (l & 15)) * 128 + pcb);
            #pragma unroll
            for (int nn = 0; nn < 4; ++nn) {
                f16x8 bh = *(const f16x8*)((const char*)&lds[8192] + (wc * 64 + nn * 16 + (l & 15)) * 128 + pcb);
                #pragma unroll
                for (int m = 0; m < 4; ++m)
                    acc[m][nn] = __builtin_amdgcn_mfma_f32_16x16x32_f16(ah[m], bh, acc[m][nn], 0, 0, 0);
            }
        }
        __syncthreads();
    }

    // ---- epilogue: scores in place, then 4-pass selection -> per-half top-4 ----
    #pragma unroll
    for (int nn = 0; nn < 4; ++nn) {
        int c = nb * 128 + wc * 64 + nn * 16 + (l & 15);
        float e2 = e2f[c];
        #pragma unroll
        for (int m = 0; m < 4; ++m)
            #pragma unroll
            for (int r = 0; r < 4; ++r)
                acc[m][nn][r] = fmaf(-2.f / 1024.f, acc[m][nn][r], e2);   // unscaled score
    }

    float* exv = (float*)lds;              // [128 rows][2 halves][4]
    int*   exi = (int*)(exv + 1024);
    int cl = nb * 128 + wc * 64 + (l & 15);
    int qq = l >> 4;

    #pragma unroll
    for (int m = 0; m < 4; ++m)
        #pragma unroll
        for (int r = 0; r < 4; ++r) {
            #pragma unroll
            for (int p = 0; p < 4; ++p) {
                float lv = acc[m][0][r]; int lcw = cl;
                #pragma unroll
                for (int nn = 1; nn < 4; ++nn) {
                    float v = acc[m][nn][r]; int cc = cl + nn * 16;
                    if (v < lv || (v == lv && cc < lcw)) { lv = v; lcw = cc; }
                }
                #pragma unroll
                for (int off = 1; off < 16; off <<= 1) {
                    float ov = __shfl_xor(lv, off, 64);
                    int   oc = __shfl_xor(lcw, off, 64);
                    if (ov < lv || (ov == lv && oc < lcw)) { lv = ov; lcw = oc; }
                }
                #pragma unroll
                for (int nn = 0; nn < 4; ++nn)
                    if (cl + nn * 16 == lcw) acc[m][nn][r] = 3.4e38f;   // remove winner
                if ((l & 15) == 0) {
                    int row = wr * 64 + m * 16 + qq * 4 + r;
                    exv[(row * 2 + wc) * 4 + p] = lv;
                    exi[(row * 2 + wc) * 4 + p] = lcw;
                }
            }
        }
    __syncthreads();
    if (t < 128) {
        int ba = (t * 2) * 4, bb = (t * 2 + 1) * 4;
        float r0 = 3.4e38f, r1 = 3.4e38f, r2 = 3.4e38f, r3 = 3.4e38f;
        int q0 = 0, q1 = 0, q2 = 0, q3 = 0;
        #pragma unroll
        for (int j = 0; j < 4; ++j) ins4(exv[ba + j], exi[ba + j], r0,q0,r1,q1,r2,q2,r3,q3);
        #pragma unroll
        for (int j = 0; j < 4; ++j) ins4(exv[bb + j], exi[bb + j], r0,q0,r1,q1,r2,q2,r3,q3);
        size_t p = (size_t)nb * N_ + (size_t)mb * 128 + t;
        pv[p] = make_float4(r0, r1, r2, r3);
        pi[p] = make_int4(q0, q1, q2, q3);
    }
}

// ---- k_merge: fold 8 sorted-4 partials -> idx, counts, cand/full classification ----
__global__ __launch_bounds__(256) void k_merge(const float4* __restrict__ pv,
                                               const int4* __restrict__ pi,
                                               const float* __restrict__ S1,
                                               int* __restrict__ idx,
                                               int* __restrict__ counts,
                                               int4* __restrict__ c4,
                                               unsigned char* __restrict__ flag,
                                               int* __restrict__ list2,
                                               int* __restrict__ nflag2) {
    int n = blockIdx.x * 256 + threadIdx.x;     // grid = 256
    float r0 = 3.4e38f, r1 = 3.4e38f, r2 = 3.4e38f, r3 = 3.4e38f;
    int q0 = 0, q1 = 0, q2 = 0, q3 = 0;
    #pragma unroll
    for (int nb = 0; nb < 8; ++nb) {
        size_t p = (size_t)nb * N_ + n;
        float4 v = pv[p]; int4 ii = pi[p];
        ins4(v.x, ii.x, r0,q0,r1,q1,r2,q2,r3,q3);
        ins4(v.y, ii.y, r0,q0,r1,q1,r2,q2,r3,q3);
        ins4(v.z, ii.z, r0,q0,r1,q1,r2,q2,r3,q3);
        ins4(v.w, ii.w, r0,q0,r1,q1,r2,q2,r3,q3);
    }
    idx[n] = q0;
    atomicAdd(&counts[q0], 1);
    float eps = fmaf(S1[n], MARGIN_A, MARGIN_B);
    bool need = (r1 - r0) < eps;
    bool full = need && ((r3 - r0) < eps);      // >3 contenders: exceedingly rare
    bool cand = need && !full;
    flag[n] = cand ? 1 : 0;
    if (cand) c4[n] = make_int4(q0, q1, q2, q3);
    unsigned long long mask = __ballot(full);
    int lane = threadIdx.x & 63;
    int cnt = __popcll(mask);
    if (cnt) {
        int base = 0;
        if (lane == 0) base = atomicAdd(nflag2, cnt);
        base = __shfl(base, 0, 64);
        if (full) {
            int pos = __popcll(mask & ((1ull << lane) - 1ull));
            list2[base + pos] = n;
        }
    }
}

// ---- k_cand: exact f64 rescore of <=4 candidates per flagged row ----
__global__ __launch_bounds__(256) void k_cand(const float* __restrict__ Z,
                                              const float* __restrict__ E,
                                              const int4* __restrict__ c4,
                                              const unsigned char* __restrict__ flag,
                                              int* __restrict__ idx,
                                              int* __restrict__ counts) {
    __shared__ float zs[32][257];
    __shared__ unsigned char sflag[32];
    __shared__ double dv[4];
    int t = threadIdx.x;
    int n0 = blockIdx.x * 32;                 // grid = 2048
    if (t < 32) sflag[t] = flag[n0 + t];
    __syncthreads();
    int any = 0;
    #pragma unroll
    for (int j = 0; j < 32; ++j) any |= sflag[j];
    if (!any) return;

    int b = n0 >> 10, hw0 = n0 & (HW_ - 1);
    int hw = t & 31, cq = t >> 5;
    const float* zb = Z + (size_t)b * (D_ * HW_) + hw0 + hw;
    #pragma unroll 4
    for (int jj = 0; jj < 32; ++jj) {
        int c = cq * 32 + jj;
        zs[hw][c] = zb[(size_t)c * HW_];      // coalesced
    }
    __syncthreads();

    int wj = t >> 6, l = t & 63;
    for (int hwi = 0; hwi < 32; ++hwi) {
        if (!sflag[hwi]) continue;            // uniform (LDS)
        int n = n0 + hwi;
        int4 cd = c4[n];
        int cj = (wj == 0) ? cd.x : (wj == 1) ? cd.y : (wj == 2) ? cd.z : cd.w;
        const float* er = E + (size_t)cj * D_;
        double s = 0.0;
        #pragma unroll
        for (int q = 0; q < 4; ++q) {
            int d = l + q * 64;
            double dz = (double)zs[hwi][d] - (double)er[d];
            s = fma(dz, dz, s);
        }
        #pragma unroll
        for (int off = 32; off; off >>= 1) s += __shfl_xor(s, off, 64);
        if (l == 0) dv[wj] = s;
        __syncthreads();
        if (t == 0) {
            double bv = dv[0]; int bi = cd.x;
            if (dv[1] < bv || (dv[1] == bv && cd.y < bi)) { bv = dv[1]; bi = cd.y; }
            if (dv[2] < bv || (dv[2] == bv && cd.z < bi)) { bv = dv[2]; bi = cd.z; }
            if (dv[3] < bv || (dv[3] == bv && cd.w < bi)) { bv = dv[3]; bi = cd.w; }
            int old = idx[n];
            if (bi != old) {
                idx[n] = bi;
                atomicSub(&counts[old], 1);
                atomicAdd(&counts[bi], 1);
            }
        }
        __syncthreads();
    }
}

// ---- k_rescan: exact f64 full-K fallback (expected ~0 items) ----
__global__ __launch_bounds__(256) void k_rescan(const float* __restrict__ Z,
                                                const float* __restrict__ Et,
                                                const double* __restrict__ e2d,
                                                const int* __restrict__ list2,
                                                const int* __restrict__ nflag2,
                                                int* __restrict__ idx,
                                                int* __restrict__ counts) {
    __shared__ float  zs[256];
    __shared__ double rv[256];
    __shared__ int    ri[256];
    int t = threadIdx.x;
    int nf = *nflag2;
    for (int ii = blockIdx.x; ii < nf; ii += 512) {      // grid = 512
        int n = list2[ii];
        int b = n >> 10, hw = n & (HW_ - 1);
        zs[t] = Z[(size_t)b * (D_ * HW_) + (size_t)t * HW_ + hw];
        __syncthreads();
        rv[t] = (double)zs[t] * (double)zs[t];
        __syncthreads();
        for (int off = 128; off; off >>= 1) {
            if (t < off) rv[t] += rv[t + off];
            __syncthreads();
        }
        double z2 = rv[0];
        __syncthreads();

        double s0 = 0.0, s1 = 0.0, s2 = 0.0, s3 = 0.0;
        #pragma unroll 4
        for (int d = 0; d < 256; ++d) {
            double zv = (double)zs[d];
            float4 e4 = *(const float4*)(Et + (size_t)d * K_ + 4 * t);
            s0 = fma(zv, (double)e4.x, s0);
            s1 = fma(zv, (double)e4.y, s1);
            s2 = fma(zv, (double)e4.z, s2);
            s3 = fma(zv, (double)e4.w, s3);
        }
        double best = 1e300; int bi = 0;
        double dvv[4] = { fma(-2.0, s0, z2 + e2d[4 * t + 0]),
                          fma(-2.0, s1, z2 + e2d[4 * t + 1]),
                          fma(-2.0, s2, z2 + e2d[4 * t + 2]),
                          fma(-2.0, s3, z2 + e2d[4 * t + 3]) };
        #pragma unroll
        for (int c = 0; c < 4; ++c)
            if (dvv[c] < best) { best = dvv[c]; bi = 4 * t + c; }
        rv[t] = best; ri[t] = bi;
        __syncthreads();
        for (int off = 128; off; off >>= 1) {
            if (t < off) {
                double ov = rv[t + off]; int oi = ri[t + off];
                if (ov < rv[t] || (ov == rv[t] && oi < ri[t])) { rv[t] = ov; ri[t] = oi; }
            }
            __syncthreads();
        }
        if (t == 0) {
            int I = ri[0], old = idx[n];
            if (I != old) {
                idx[n] = I;
                atomicSub(&counts[old], 1);
                atomicAdd(&counts[I], 1);
            }
        }
        __syncthreads();
    }
}

// ---- k_gather: z_q out (NCHW) via LDS-staged e-rows + f64 loss ----
__global__ __launch_bounds__(256) void k_gather(const float* __restrict__ Z,
                                                const float* __restrict__ E,
                                                const int* __restrict__ idx,
                                                float* __restrict__ out_zq,
                                                double* __restrict__ loss_acc) {
    __shared__ float ecache[32][257];
    __shared__ int sidx[32];
    __shared__ double wls[4];
    int t = threadIdx.x;
    int n0 = blockIdx.x * 32;                 // grid = 2048
    int b = n0 >> 10, hw0 = n0 & (HW_ - 1);
    if (t < 32) sidx[t] = idx[n0 + t];
    __syncthreads();
    #pragma unroll 8
    for (int j = 0; j < 32; ++j)
        ecache[j][t] = E[(size_t)sidx[j] * D_ + t];
    __syncthreads();
    int hw = t & 31, cq = t >> 5;
    const float* zb = Z      + (size_t)b * (D_ * HW_) + hw0 + hw;
    float*       ob = out_zq + (size_t)b * (D_ * HW_) + hw0 + hw;
    double ls = 0.0;
    #pragma unroll 4
    for (int jj = 0; jj < 32; ++jj) {
        int c = cq * 32 + jj;
        float e = ecache[hw][c];
        float z = zb[(size_t)c * HW_];
        ob[(size_t)c * HW_] = e;
        double dz = (double)z - (double)e;
        ls = fma(dz, dz, ls);
    }
    #pragma unroll
    for (int off = 32; off; off >>= 1) ls += __shfl_xor(ls, off, 64);
    int wv = t >> 6;
    if ((t & 63) == 0) wls[wv] = ls;
    __syncthreads();
    if (t == 0) atomicAdd(loss_acc, wls[0] + wls[1] + wls[2] + wls[3]);
}

// ---- k_final ----
__global__ __launch_bounds__(256) void k_final(const int* __restrict__ counts,
                                               const double* __restrict__ loss_acc,
                                               float* __restrict__ out) {
    __shared__ double sh[256];
    int t = threadIdx.x;
    double s = 0.0;
    for (int k = t; k < K_; k += 256) {
        double p = (double)counts[k] / (double)N_;
        s += p * log(p + 1e-10);
    }
    sh[t] = s; __syncthreads();
    for (int off = 128; off; off >>= 1) {
        if (t < off) sh[t] += sh[t + off];
        __syncthreads();
    }
    if (t == 0) {
        out[0]       = (float)((*loss_acc) / (double)ND_ * 1.25);
        out[1 + ND_] = (float)exp(-sh[0]);
    }
}

extern "C" void kernel_launch(void* const* d_in, const int* in_sizes, int n_in,
                              void* d_out, int out_size, void* d_ws, size_t ws_size,
                              hipStream_t stream) {
    (void)in_sizes; (void)n_in; (void)out_size; (void)ws_size;
    const float* Z = (const float*)d_in[0];
    const float* E = (const float*)d_in[1];
    float* out = (float*)d_out;

    char* ws = (char*)d_ws;
    unsigned short* Zh       = (unsigned short*)(ws);              // 32 MB
    unsigned short* Eh       = (unsigned short*)(ws + 33554432);   // 512 KB
    float*          Et       = (float*)(ws + 34078720);            // 1 MB
    float*          e2f      = (float*)(ws + 35127296);            // 4 KB
    double*         e2d      = (double*)(ws + 35131392);           // 8 KB
    float*          S1       = (float*)(ws + 35139584);            // 256 KB
    float4*         pv       = (float4*)(ws + 35401728);           // 8 MB
    int4*           pi       = (int4*)  (ws + 43790336);           // 8 MB
    int4*           c4       = (int4*)  (ws + 52178944);           // 1 MB
    int*            idx      = (int*)   (ws + 53227520);           // 256 KB
    unsigned char*  flag     = (unsigned char*)(ws + 53489664);    // 64 KB
    int*            list2    = (int*)   (ws + 53555200);           // 256 KB
    int*            counts   = (int*)   (ws + 53817344);           // 4 KB
    int*            nflag2   = (int*)   (ws + 53821440);           // 64 B
    double*         loss_acc = (double*)(ws + 53821504);           // 8 B

    k_init  <<<dim3(1024), dim3(256), 0, stream>>>(E, Eh, Et, e2f, e2d, counts, nflag2, loss_acc);
    k_zsplit<<<dim3(2048), dim3(256), 0, stream>>>(Z, Zh, S1);
    k_phase1<<<dim3(4096), dim3(256), 0, stream>>>(Zh, Eh, e2f, pv, pi);
    k_merge <<<dim3(256),  dim3(256), 0, stream>>>(pv, pi, S1, idx, counts, c4, flag, list2, nflag2);
    k_cand  <<<dim3(2048), dim3(256), 0, stream>>>(Z, E, c4, flag, idx, counts);
    k_rescan<<<dim3(512),  dim3(256), 0, stream>>>(Z, Et, e2d, list2, nflag2, idx, counts);
    k_gather<<<dim3(2048), dim3(256), 0, stream>>>(Z, E, idx, out + 1, loss_acc);
    k_final <<<1,          dim3(256), 0, stream>>>(counts, loss_acc, out);
}